// Round 10
// baseline (474.966 us; speedup 1.0000x reference)
//
#include <hip/hip_runtime.h>
#include <hip/hip_fp16.h>

// Fixed problem shape
#define TOK   64
#define INF   4096
#define OUTF  11008
#define NUMEL (OUTF * INF)        // 45088768
#define NSLC  (NUMEL / 64)        // 704512 64-element slices
#define NBLK  (OUTF / 16)         // 688 GEMM blocks

// Harness dtypes: fp16 arrays arrive as fp32; ints as int32; output fp32.
typedef __attribute__((ext_vector_type(8))) _Float16 half8;
typedef __attribute__((ext_vector_type(4))) _Float16 half4;
typedef __attribute__((ext_vector_type(4))) float floatx4;
typedef __attribute__((ext_vector_type(4), aligned(4))) int int4u;  // dword-aligned dwordx4

// ---------------------------------------------------------------------------
// Precompute: (a) x fp32 -> fp16 (512 KB, L2-resident GEMM A),
// (b) cum64[s] = lower_bound(fp16_pos, 64*s) — independent binary searches,
// latency fully overlapped (R5/R9-verified).
// ---------------------------------------------------------------------------
__global__ __launch_bounds__(256) void precompute_kernel(
    const float* __restrict__ x, const int* __restrict__ fppos, int nf,
    _Float16* __restrict__ x16, int* __restrict__ cum64) {
  const int t = blockIdx.x * 256 + threadIdx.x;
  if (t < (TOK * INF) / 4) {
    const floatx4 f = *(const floatx4*)&x[t * 4];
    half4 h;
    h[0] = (_Float16)f[0]; h[1] = (_Float16)f[1];
    h[2] = (_Float16)f[2]; h[3] = (_Float16)f[3];
    *(half4*)&x16[t * 4] = h;
  }
  if (t <= NSLC) {
    const int target = t << 6;
    int lo = 0, hi = nf;
    while (lo < hi) {
      const int mid = (lo + hi) >> 1;
      if (fppos[mid] < target) lo = mid + 1; else hi = mid;
    }
    cum64[t] = lo;
  }
}

// ---------------------------------------------------------------------------
// Dequant v4: thread owns 16 POSITIONED slots [16t,16t+16). Since
// 16t mod 64 ∈ {0,16,32,48}, the whole run lies in ONE 64-slice -> one cum64
// pair, one scale, per-element overhead halved vs R9. Loads: 4 dword-aligned
// dwordx4; stores: 2 aligned half8. Outliers: 2 predicated probes + rare
// loop (slice mean 0.177, P(>2)~1e-4); rare repair path consumes only
// values already in the 16 loaded dwords.
// ---------------------------------------------------------------------------
__global__ __launch_bounds__(256) void dequant_kernel(
    const int* __restrict__ i8, const float* __restrict__ fpdat,
    const int* __restrict__ fppos, const float* __restrict__ scales,
    const int* __restrict__ cum64, _Float16* __restrict__ W, int n8) {
  const int t   = blockIdx.x * 256 + threadIdx.x;
  const int p0  = t * 16;
  const int s64 = p0 >> 6;
  const int c0  = cum64[s64];
  const int c1  = cum64[s64 + 1];
  const float s = scales[p0 >> 10];

  int lt = 0, f = 0;
  float ov[16];
#pragma unroll
  for (int e = 0; e < 16; ++e) ov[e] = 0.f;

  const int w = c1 - c0;
  if (w > 0) {
#pragma unroll 2
    for (int j = 0; j < 2; ++j) {
      if (j < w) {
        const int d = fppos[c0 + j] - p0;
        const float v = fpdat[c0 + j];
        lt += (d < 0);
        if ((unsigned)d < 16u) {
          f |= 1 << d;
#pragma unroll
          for (int e = 0; e < 16; ++e) ov[e] = (d == e) ? v : ov[e];
        }
      }
    }
    for (int j = 2; j < w; ++j) {  // P ~ 1e-4 fallback
      const int d = fppos[c0 + j] - p0;
      const float v = fpdat[c0 + j];
      lt += (d < 0);
      if ((unsigned)d < 16u) {
        f |= 1 << d;
#pragma unroll
        for (int e = 0; e < 16; ++e) ov[e] = (d == e) ? v : ov[e];
      }
    }
  }

  const int i0 = p0 - c0 - lt;  // compacted index of position p0
  half8 oh0, oh1;
  if (i0 + 16 <= n8) {
    int l[16];
    *(int4u*)&l[0]  = *(const int4u*)&i8[i0];
    *(int4u*)&l[4]  = *(const int4u*)&i8[i0 + 4];
    *(int4u*)&l[8]  = *(const int4u*)&i8[i0 + 8];
    *(int4u*)&l[12] = *(const int4u*)&i8[i0 + 12];
    if (f == 0) {
#pragma unroll
      for (int e = 0; e < 8; ++e) oh0[e] = (_Float16)((float)l[e] * s);
#pragma unroll
      for (int e = 0; e < 8; ++e) oh1[e] = (_Float16)((float)l[8 + e] * s);
    } else {
      // Rare repair: walk register file l[q]; outlier slots take fp values.
      int q = 0;
#pragma unroll
      for (int e = 0; e < 16; ++e) {
        const int flg = (f >> e) & 1;
        int lv = l[0];
#pragma unroll
        for (int qq = 1; qq < 16; ++qq) lv = (q == qq) ? l[qq] : lv;
        const _Float16 hv = flg ? (_Float16)ov[e] : (_Float16)((float)lv * s);
        if (e < 8) oh0[e] = hv; else oh1[e - 8] = hv;
        q += 1 - flg;
      }
    }
  } else {
    // Array-tail path (last block only): clamped scalar loads.
    int c = 0;
    const int m = n8 - 1;
#pragma unroll
    for (int e = 0; e < 16; ++e) {
      const int flg = (f >> e) & 1;
      int idx = i0 + e - c;
      idx = idx < 0 ? 0 : (idx > m ? m : idx);
      const _Float16 hv = flg ? (_Float16)ov[e] : (_Float16)((float)i8[idx] * s);
      if (e < 8) oh0[e] = hv; else oh1[e - 8] = hv;
      c += flg;
    }
  }
  *(half8*)&W[p0]     = oh0;
  *(half8*)&W[p0 + 8] = oh1;
}

// ---------------------------------------------------------------------------
// GEMM v4: out = x @ W^T + bias. 688 blocks x 8 waves (512 thr): block owns
// rows [nt*16,+16); wave w owns K [512w,+512) = 16 steps of 32; full M=64 as
// 4 MFMA tiles. LDS reduce over 8 waves -> DIRECT store (no atomics, no
// out-memset — R9's epilogue cost). 4 blocks/CU (32-wave cap) >= grid
// 2.7/CU -> fully resident.
// mfma_f32_16x16x32_f16: A/B frag idx=lane&15, k=quad*8+j; D row=quad*4+i,
// col=lane&15  [verified R2-R9].
// ---------------------------------------------------------------------------
__global__ __launch_bounds__(512) void gemm_kernel(
    const _Float16* __restrict__ x16, const _Float16* __restrict__ W,
    const float* __restrict__ bias, float* __restrict__ out) {
  __shared__ float red[8 * 64 * 16];  // 32 KB

  const int tid  = threadIdx.x;
  const int wave = tid >> 6;
  const int lane = tid & 63;
  const int quad = lane >> 4;
  const int ln   = lane & 15;
  const int n0   = blockIdx.x * 16;

  const int kb = wave * 512 + quad * 8;
  const _Float16* wp = &W[(n0 + ln) * INF + kb];
  const _Float16* ap = &x16[ln * INF + kb];

  floatx4 acc0 = {0,0,0,0}, acc1 = {0,0,0,0}, acc2 = {0,0,0,0}, acc3 = {0,0,0,0};
#pragma unroll 4
  for (int st = 0; st < 16; ++st) {
    const int ko = st * 32;
    const half8 bh = *(const half8*)&wp[ko];
    const half8 a0 = *(const half8*)&ap[ko];
    const half8 a1 = *(const half8*)&ap[16 * INF + ko];
    const half8 a2 = *(const half8*)&ap[32 * INF + ko];
    const half8 a3 = *(const half8*)&ap[48 * INF + ko];
    acc0 = __builtin_amdgcn_mfma_f32_16x16x32_f16(a0, bh, acc0, 0, 0, 0);
    acc1 = __builtin_amdgcn_mfma_f32_16x16x32_f16(a1, bh, acc1, 0, 0, 0);
    acc2 = __builtin_amdgcn_mfma_f32_16x16x32_f16(a2, bh, acc2, 0, 0, 0);
    acc3 = __builtin_amdgcn_mfma_f32_16x16x32_f16(a3, bh, acc3, 0, 0, 0);
  }

  const int mb = quad * 4;
#pragma unroll
  for (int i = 0; i < 4; ++i) red[wave * 1024 + (mb + i)      * 16 + ln] = acc0[i];
#pragma unroll
  for (int i = 0; i < 4; ++i) red[wave * 1024 + (16 + mb + i) * 16 + ln] = acc1[i];
#pragma unroll
  for (int i = 0; i < 4; ++i) red[wave * 1024 + (32 + mb + i) * 16 + ln] = acc2[i];
#pragma unroll
  for (int i = 0; i < 4; ++i) red[wave * 1024 + (48 + mb + i) * 16 + ln] = acc3[i];
  __syncthreads();

#pragma unroll
  for (int c2 = 0; c2 < 2; ++c2) {
    const int cell = tid + c2 * 512;  // 1024 cells = 64 m x 16 n
    const int mm = cell >> 4, nn = cell & 15;
    float v = bias[n0 + nn];
#pragma unroll
    for (int wv = 0; wv < 8; ++wv) v += red[wv * 1024 + cell];
    out[mm * OUTF + n0 + nn] = v;
  }
}

// ---------------------------------------------------------------------------
// Inputs: 0 x(fp32) 1 int8_data(i32) 2 fp16_data(fp32) 3 scales(fp32)
// 4 bias(fp32) 5 int8_pos(UNUSED) 6 fp16_pos(i32) 7 block_idx(UNUSED)
// ws: W fp16 (90.2 MB) | x16 (512 KB) | cum64 (2.82 MB)
// ---------------------------------------------------------------------------
extern "C" void kernel_launch(void* const* d_in, const int* in_sizes, int n_in,
                              void* d_out, int out_size, void* d_ws,
                              size_t ws_size, hipStream_t stream) {
  const float* x      = (const float*)d_in[0];
  const int*   i8     = (const int*)d_in[1];
  const float* fpdat  = (const float*)d_in[2];
  const float* scales = (const float*)d_in[3];
  const float* bias   = (const float*)d_in[4];
  const int*   fppos  = (const int*)d_in[6];

  char* wsp = (char*)d_ws;
  _Float16* W     = (_Float16*)wsp;
  _Float16* x16   = (_Float16*)(wsp + (size_t)NUMEL * sizeof(_Float16));
  int*      cum64 = (int*)(wsp + (size_t)NUMEL * sizeof(_Float16)
                               + (size_t)TOK * INF * sizeof(_Float16));
  float*    out   = (float*)d_out;

  const int n8 = in_sizes[1];
  const int nf = in_sizes[2];

  precompute_kernel<<<(NSLC + 256) / 256 + 1, 256, 0, stream>>>(x, fppos, nf,
                                                                x16, cum64);
  dequant_kernel<<<NUMEL / (16 * 256), 256, 0, stream>>>(i8, fpdat, fppos,
                                                         scales, cum64, W, n8);
  gemm_kernel<<<NBLK, 512, 0, stream>>>(x16, W, bias, out);
}